// Round 9
// baseline (2108.800 us; speedup 1.0000x reference)
//
#include <hip/hip_runtime.h>
#include <hip/hip_bf16.h>
#include <cmath>

// Problem constants
#define N_   128
#define T_   64
#define D_   1024
#define H_   1024
#define G4_  4096   // 4*H
#define K2   2048   // recurrent GEMM K: x | h

typedef short bf16x8 __attribute__((ext_vector_type(8)));
typedef float f32x4  __attribute__((ext_vector_type(4)));

__device__ __forceinline__ unsigned short f2bf(float f) {
    union { float f; unsigned int u; } v; v.f = f;
    unsigned int r = (v.u + 0x7FFFu + ((v.u >> 16) & 1u)) >> 16;  // RNE
    return (unsigned short)r;
}
__device__ __forceinline__ float bf2f(unsigned short s) {
    union { unsigned int u; float f; } v; v.u = ((unsigned int)s) << 16;
    return v.f;
}

// ---------------------------------------------------------------- prep ----

__global__ void k_convert_x(const float* __restrict__ x, unsigned short* __restrict__ xbf) {
    long i = ((long)blockIdx.x * blockDim.x + threadIdx.x) * 8;
    float4 a = *(const float4*)(x + i);
    float4 b = *(const float4*)(x + i + 4);
    union { unsigned short s[8]; uint4 v; } o;
    o.s[0] = f2bf(a.x); o.s[1] = f2bf(a.y); o.s[2] = f2bf(a.z); o.s[3] = f2bf(a.w);
    o.s[4] = f2bf(b.x); o.s[5] = f2bf(b.y); o.s[6] = f2bf(b.z); o.s[7] = f2bf(b.w);
    *(uint4*)(xbf + i) = o.v;
}

// out[c][ocoff + r] = bf16(in[r][c]); in is R x C (f32), out rows stride ors.
__global__ void k_transpose(const float* __restrict__ in, unsigned short* __restrict__ out,
                            int R, int C, long ors, long ocoff) {
    __shared__ float tile[32][33];
    int c0 = blockIdx.x * 32, r0 = blockIdx.y * 32;
    int tx = threadIdx.x, ty = threadIdx.y;  // (32, 8)
    for (int yy = ty; yy < 32; yy += 8) {
        int r = r0 + yy, c = c0 + tx;
        if (r < R && c < C) tile[yy][tx] = in[(long)r * C + c];
    }
    __syncthreads();
    for (int yy = ty; yy < 32; yy += 8) {
        int oc = c0 + yy, orr = r0 + tx;
        if (oc < C && orr < R) out[(long)oc * ors + ocoff + orr] = f2bf(tile[tx][yy]);
    }
}

// Af2[n][h][p] bf16 (A layout) and AfT[(n*16+p)][h] bf16 (transposed).
__global__ void k_afdual(const float* __restrict__ A, unsigned short* __restrict__ Af2,
                         unsigned short* __restrict__ AfT) {
    int n = blockIdx.x, hc = blockIdx.y * 64;
    int tid = threadIdx.x;
    int hl = tid >> 2, p4 = (tid & 3) * 4;
    __shared__ float ldsT[16][65];
    const float* src = A + ((long)n * H_ + hc + hl) * 16 + p4;
    float4 v = *(const float4*)src;
    unsigned short o[4] = {f2bf(v.x), f2bf(v.y), f2bf(v.z), f2bf(v.w)};
    *(uint2*)(Af2 + ((long)n * H_ + hc + hl) * 16 + p4) = *(uint2*)o;
    ldsT[p4 + 0][hl] = v.x; ldsT[p4 + 1][hl] = v.y;
    ldsT[p4 + 2][hl] = v.z; ldsT[p4 + 3][hl] = v.w;
    __syncthreads();
    int p = tid >> 4, hs = (tid & 15) * 4;
    unsigned short q[4] = {f2bf(ldsT[p][hs]), f2bf(ldsT[p][hs + 1]),
                           f2bf(ldsT[p][hs + 2]), f2bf(ldsT[p][hs + 3])};
    *(uint2*)(AfT + ((long)n * 16 + p) * (long)H_ + hc + hs) = *(uint2*)q;
}

// h0 = mean_p A; c0 = h0; bf16 copy into hbf0
__global__ void k_h0(const float* __restrict__ A, float* __restrict__ h,
                     float* __restrict__ c, unsigned short* __restrict__ hbf0) {
    long id = (long)blockIdx.x * blockDim.x + threadIdx.x;
    const float4* ap = (const float4*)(A + id * 16);
    float s = 0.f;
    #pragma unroll
    for (int q = 0; q < 4; q++) { float4 v = ap[q]; s += v.x + v.y + v.z + v.w; }
    float m = s * (1.0f / 16.0f);
    h[id] = m; c[id] = m; hbf0[id] = f2bf(m);
}

// t=0 score partials: partial0[n][p][jt] = sum_{jh in jt tile} h0[jh]*Af2[n][jh][p]
__global__ __launch_bounds__(512)
void k_part0(const float* __restrict__ hbuf, const unsigned short* __restrict__ Af2,
             float* __restrict__ partial0) {
    int n = blockIdx.x;
    int tid = threadIdx.x;
    int jh = tid * 2;
    float sp[16];
    #pragma unroll
    for (int p = 0; p < 16; p++) sp[p] = 0.f;
    #pragma unroll
    for (int u = 0; u < 2; u++) {
        float hv = hbuf[(long)n * H_ + jh + u];
        const unsigned short* afp = Af2 + ((long)n * H_ + jh + u) * 16;
        bf16x8 a0 = *(const bf16x8*)(afp);
        bf16x8 a1 = *(const bf16x8*)(afp + 8);
        #pragma unroll
        for (int p = 0; p < 8; p++) { sp[p] += hv * bf2f((unsigned short)a0[p]);
                                      sp[8+p] += hv * bf2f((unsigned short)a1[p]); }
    }
    #pragma unroll
    for (int off = 1; off < 8; off <<= 1) {
        #pragma unroll
        for (int p = 0; p < 16; p++) sp[p] += __shfl_xor(sp[p], off);
    }
    int jt = tid >> 3;
    if ((tid & 7) == 0) {
        #pragma unroll
        for (int p = 0; p < 16; p++)
            partial0[((long)n * 16 + p) * 64 + jt] = sp[p];
    }
}

// AW[(n*4096 + j)*16 + p] bf16 = sum_h AfT[n*16+p][h] * WattnT[j][h]
// grid (64 jN, 32 mt): 64x64 tile, 256 thr = 4 row-waves, full K=1024, no LDS.
__global__ __launch_bounds__(256, 4)
void k_aw(const unsigned short* __restrict__ AfT, const unsigned short* __restrict__ WattnT,
          unsigned short* __restrict__ AW) {
    int wv = threadIdx.x >> 6, lane = threadIdx.x & 63;
    int cl = lane & 15, kg = lane >> 4;
    int mbase = blockIdx.y * 64 + wv * 16, jbase = blockIdx.x * 64;

    f32x4 acc[4];
    #pragma unroll
    for (int s = 0; s < 4; s++) acc[s] = (f32x4){0.f, 0.f, 0.f, 0.f};
    const unsigned short* ap = AfT + (long)(mbase + cl) * H_ + kg * 8;
    const unsigned short* bp[4];
    #pragma unroll
    for (int s = 0; s < 4; s++)
        bp[s] = WattnT + (long)(jbase + s * 16 + cl) * H_ + kg * 8;
    #pragma unroll
    for (int k0 = 0; k0 < 1024; k0 += 32) {
        bf16x8 a = *(const bf16x8*)(ap + k0);
        #pragma unroll
        for (int s = 0; s < 4; s++) {
            bf16x8 bb = *(const bf16x8*)(bp[s] + k0);
            acc[s] = __builtin_amdgcn_mfma_f32_16x16x32_bf16(a, bb, acc[s], 0, 0, 0);
        }
    }
    // C write: n fixed per wave; p = 4*kg + v (4 consecutive bf16 = 8B packed)
    int n = mbase >> 4;   // mbase is 16-aligned
    #pragma unroll
    for (int s = 0; s < 4; s++) {
        int j = jbase + s * 16 + cl;
        unsigned short q[4] = {f2bf(acc[s][0]), f2bf(acc[s][1]),
                               f2bf(acc[s][2]), f2bf(acc[s][3])};
        *(uint2*)(AW + ((long)n * G4_ + j) * 16 + kg * 4) = *(uint2*)q;
    }
}

// ------------------------------------------------------------- per step ----

// ONE kernel per step. grid (64 jt, 8 rt), 512 thr = 8 waves (ks:4 x gp:2).
// Front: softmax w[16] per n from partIN (prev step). GEMM: act = [xt|h]@WxhT^T.
// Epilogue: + w.AW + b, gates, c/h update, score partials for t+1 -> partOUT.
// XCD = bid%8 = jt%8: per-XCD WxhT/AW slices (~4MB) L2-resident across steps.
__global__ __launch_bounds__(512, 4)
void k_step(const unsigned short* __restrict__ xbf,     // [N][T][D]
            const unsigned short* __restrict__ hbf_in,  // [N][H]
            unsigned short* __restrict__ hbf_out,       // [N][H]
            const unsigned short* __restrict__ WxhT,    // [4096][2048]
            const unsigned short* __restrict__ AW,      // [N][4096][16]
            const unsigned short* __restrict__ Af2,     // [N][H][16]
            const float* __restrict__ partIN,           // [N][16][64]
            float* __restrict__ partOUT,                // [N][16][64]
            const float* __restrict__ bvec,             // [4096]
            float* __restrict__ c,
            float* __restrict__ out, int t) {
    int tid  = threadIdx.x;
    int wv   = tid >> 6, lane = tid & 63;
    int ks   = wv & 3;             // K-quarter of 2048
    int gp   = wv >> 2;            // gate pair
    int cl   = lane & 15, kg = lane >> 4;
    int jt   = blockIdx.x;
    int colbase = jt * 16;
    int rowbase = blockIdx.y * 16;

    __shared__ float wsm[16][17];
    __shared__ float red[3][2][64][9];
    __shared__ float act[4][16][17];

    // ---- score front: w[16] for the block's 16 n's ----
    {
        int nl = tid >> 5;              // 0..15
        int tt = tid & 31;
        int p  = tt & 15, ch = tt >> 4; // jt-half
        const float* src = partIN + ((long)(rowbase + nl) * 16 + p) * 64 + ch * 32;
        float s = 0.f;
        #pragma unroll
        for (int q = 0; q < 32; q++) s += src[q];
        s += __shfl_xor(s, 16);
        s *= (1.0f / 32.0f);            // /sqrt(H)
        float m = s;
        #pragma unroll
        for (int off = 1; off < 16; off <<= 1) m = fmaxf(m, __shfl_xor(m, off));
        float e = expf(s - m);
        float sum = e;
        #pragma unroll
        for (int off = 1; off < 16; off <<= 1) sum += __shfl_xor(sum, off);
        if (ch == 0) wsm[nl][p] = e / sum;
    }

    // ---- GEMM: 16 rows x 16 jh x 2 gates over K-quarter 512 ----
    f32x4 acc0 = (f32x4){0.f,0.f,0.f,0.f};
    f32x4 acc1 = (f32x4){0.f,0.f,0.f,0.f};
    int r0 = rowbase + cl;
    const unsigned short* ap = (ks < 2)
        ? xbf    + ((long)r0 * T_ + t) * D_ + (ks & 1) * 512 + kg * 8
        : hbf_in + (long)r0 * H_           + (ks & 1) * 512 + kg * 8;
    int g0 = gp * 2;
    const unsigned short* b0 = WxhT + (long)((g0    ) * 1024 + colbase + cl) * K2 + ks * 512 + kg * 8;
    const unsigned short* b1 = WxhT + (long)((g0 + 1) * 1024 + colbase + cl) * K2 + ks * 512 + kg * 8;
    #pragma unroll
    for (int k0 = 0; k0 < 512; k0 += 32) {
        bf16x8 a  = *(const bf16x8*)(ap + k0);
        bf16x8 v0 = *(const bf16x8*)(b0 + k0);
        bf16x8 v1 = *(const bf16x8*)(b1 + k0);
        acc0 = __builtin_amdgcn_mfma_f32_16x16x32_bf16(a, v0, acc0, 0, 0, 0);
        acc1 = __builtin_amdgcn_mfma_f32_16x16x32_bf16(a, v1, acc1, 0, 0, 0);
    }

    // ---- 4-way K reduce ----
    if (ks != 0) {
        #pragma unroll
        for (int v = 0; v < 4; v++) {
            red[ks - 1][gp][lane][v]     = acc0[v];
            red[ks - 1][gp][lane][4 + v] = acc1[v];
        }
    }
    __syncthreads();
    if (ks == 0) {
        #pragma unroll
        for (int v = 0; v < 4; v++) {
            float s0 = acc0[v] + red[0][gp][lane][v]     + red[1][gp][lane][v]     + red[2][gp][lane][v];
            float s1 = acc1[v] + red[0][gp][lane][4 + v] + red[1][gp][lane][4 + v] + red[2][gp][lane][4 + v];
            act[g0    ][kg * 4 + v][cl] = s0;   // C/D row = 4*kg + v
            act[g0 + 1][kg * 4 + v][cl] = s1;
        }
    }
    __syncthreads();

    // ---- epilogue: 256 threads x 1 (n, jh) cell ----
    if (tid < 256) {
        int nloc = tid >> 4, jl = tid & 15;
        int n = rowbase + nloc, jh = colbase + jl;
        float wv16[16];
        #pragma unroll
        for (int p = 0; p < 16; p++) wv16[p] = wsm[nloc][p];

        float s4[4];
        #pragma unroll
        for (int g = 0; g < 4; g++) {
            int j = g * 1024 + jh;
            const unsigned short* awp = AW + ((long)n * G4_ + j) * 16;
            bf16x8 aw0 = *(const bf16x8*)(awp);
            bf16x8 aw1 = *(const bf16x8*)(awp + 8);
            float at = 0.f;
            #pragma unroll
            for (int p = 0; p < 8; p++) at += wv16[p]     * bf2f((unsigned short)aw0[p]);
            #pragma unroll
            for (int p = 0; p < 8; p++) at += wv16[8 + p] * bf2f((unsigned short)aw1[p]);
            s4[g] = act[g][nloc][jl] + at + bvec[j];
        }
        float ig = 1.f / (1.f + expf(-s4[0]));
        float fg = 1.f / (1.f + expf(-s4[1]));
        float og = 1.f / (1.f + expf(-s4[2]));
        float gg = tanhf(s4[3]);
        long idx = (long)n * H_ + jh;
        float cn = fg * c[idx] + ig * gg;
        float hn = og * tanhf(cn);
        c[idx] = cn;
        hbf_out[idx] = f2bf(hn);
        out[((long)n * T_ + t) * H_ + jh] = hn;

        // score partials for t+1
        const unsigned short* afp = Af2 + ((long)n * H_ + jh) * 16;
        bf16x8 af0 = *(const bf16x8*)(afp);
        bf16x8 af1 = *(const bf16x8*)(afp + 8);
        float sp[16];
        #pragma unroll
        for (int p = 0; p < 8; p++) { sp[p]     = hn * bf2f((unsigned short)af0[p]);
                                      sp[8 + p] = hn * bf2f((unsigned short)af1[p]); }
        #pragma unroll
        for (int off = 1; off < 16; off <<= 1) {
            #pragma unroll
            for (int p = 0; p < 16; p++) sp[p] += __shfl_xor(sp[p], off);
        }
        float outv = 0.f;
        #pragma unroll
        for (int p = 0; p < 16; p++) if (jl == p) outv = sp[p];
        partOUT[((long)n * 16 + jl) * 64 + jt] = outv;
    }
}

// ---------------------------------------------------------------- launch ----

extern "C" void kernel_launch(void* const* d_in, const int* in_sizes, int n_in,
                              void* d_out, int out_size, void* d_ws, size_t ws_size,
                              hipStream_t stream) {
    const float* x     = (const float*)d_in[0];
    const float* A     = (const float*)d_in[1];
    const float* Wx    = (const float*)d_in[2];
    const float* Wh    = (const float*)d_in[3];
    const float* Wattn = (const float*)d_in[4];
    const float* b     = (const float*)d_in[5];
    float* out = (float*)d_out;

    char* ws = (char*)d_ws;
    size_t off = 0;
    auto alloc = [&](size_t bytes) -> void* {
        void* p = ws + off;
        off += (bytes + 255) & ~(size_t)255;
        return p;
    };
    unsigned short* xbf    = (unsigned short*)alloc((size_t)N_ * T_ * D_ * 2);
    unsigned short* WxhT   = (unsigned short*)alloc((size_t)G4_ * K2 * 2);
    unsigned short* WattnT = (unsigned short*)alloc((size_t)G4_ * H_ * 2);
    unsigned short* AfT    = (unsigned short*)alloc((size_t)N_ * 16 * H_ * 2);
    unsigned short* Af2    = (unsigned short*)alloc((size_t)N_ * H_ * 16 * 2);
    unsigned short* AW     = (unsigned short*)alloc((size_t)N_ * G4_ * 16 * 2);
    float*          hbuf   = (float*)alloc((size_t)N_ * H_ * 4);
    float*          cbuf   = (float*)alloc((size_t)N_ * H_ * 4);
    unsigned short* hbf0   = (unsigned short*)alloc((size_t)N_ * H_ * 2);
    unsigned short* hbf1   = (unsigned short*)alloc((size_t)N_ * H_ * 2);
    float*          part0  = (float*)alloc((size_t)N_ * 16 * 64 * 4);
    float*          part1  = (float*)alloc((size_t)N_ * 16 * 64 * 4);

    // prep
    k_convert_x<<<dim3((N_ * T_ * D_) / (256 * 8)), dim3(256), 0, stream>>>(x, xbf);
    k_transpose<<<dim3(G4_ / 32, D_ / 32), dim3(32, 8), 0, stream>>>(Wx,    WxhT,   D_, G4_, (long)K2, 0L);
    k_transpose<<<dim3(G4_ / 32, H_ / 32), dim3(32, 8), 0, stream>>>(Wh,    WxhT,   H_, G4_, (long)K2, 1024L);
    k_transpose<<<dim3(G4_ / 32, H_ / 32), dim3(32, 8), 0, stream>>>(Wattn, WattnT, H_, G4_, (long)H_, 0L);
    k_afdual<<<dim3(N_, 16), dim3(256), 0, stream>>>(A, Af2, AfT);
    k_h0<<<dim3((N_ * H_) / 256), dim3(256), 0, stream>>>(A, hbuf, cbuf, hbf0);
    k_part0<<<dim3(N_), dim3(512), 0, stream>>>(hbuf, Af2, part0);
    k_aw<<<dim3(G4_ / 64, (N_ * 16) / 64), dim3(256), 0, stream>>>(AfT, WattnT, AW);

    // recurrence: ONE kernel per step
    for (int t = 0; t < T_; t++) {
        unsigned short* hin  = (t & 1) ? hbf1 : hbf0;
        unsigned short* hout = (t & 1) ? hbf0 : hbf1;
        float* pIN  = (t & 1) ? part1 : part0;
        float* pOUT = (t & 1) ? part0 : part1;
        k_step<<<dim3(64, 8), dim3(512), 0, stream>>>(xbf, hin, hout, WxhT, AW, Af2,
                                                      pIN, pOUT, b, cbuf, out, t);
    }
}

// Round 10
// 1140.565 us; speedup vs baseline: 1.8489x; 1.8489x over previous
//
#include <hip/hip_runtime.h>
#include <hip/hip_bf16.h>
#include <cmath>

// Problem constants
#define N_   128
#define T_   64
#define D_   1024
#define H_   1024
#define G4_  4096   // 4*H

typedef short bf16x8 __attribute__((ext_vector_type(8)));
typedef float f32x4  __attribute__((ext_vector_type(4)));

__device__ __forceinline__ unsigned short f2bf(float f) {
    union { float f; unsigned int u; } v; v.f = f;
    unsigned int r = (v.u + 0x7FFFu + ((v.u >> 16) & 1u)) >> 16;  // RNE
    return (unsigned short)r;
}
__device__ __forceinline__ float bf2f(unsigned short s) {
    union { unsigned int u; float f; } v; v.u = ((unsigned int)s) << 16;
    return v.f;
}

// Fragment-packed layout (for mfma_f32_16x16x32_bf16, lane = kg*16+cl):
//   P[tile][kc][lane][8] bf16 : element (row = tile*16+cl, k = kc*32+kg*8+e)
//   flat ushort offset = ((tile*KCTOT + kc)*64 + lane)*8
// A wave's fragment load = base + lane*8 -> 64 x 16B = 1KB CONTIGUOUS.

// ---------------------------------------------------------------- prep ----

// pack weight src f32 [1024][4096] (k-major) -> fragment-packed B (rows = j).
__global__ void k_pack_w(const float* __restrict__ src, unsigned short* __restrict__ dst,
                         int kcoff, int kctot) {
    __shared__ float ld[64][33];
    int j0 = blockIdx.x * 32, k0 = blockIdx.y * 64;
    int tid = threadIdx.x;
    int c = tid & 31, r = tid >> 5;           // 32 j x 8 k
    #pragma unroll
    for (int i = 0; i < 8; i++)
        ld[r + i * 8][c] = src[(long)(k0 + r + i * 8) * G4_ + j0 + c];
    __syncthreads();
    int j = tid & 31, ku = tid >> 5;          // 32 j x 8 k-units of 8
    int kcl = ku >> 2, kg = ku & 3;
    int jti = (j0 + j) >> 4, cl = (j0 + j) & 15;
    int kc = kcoff + (k0 >> 5) + kcl;
    unsigned short q[8];
    #pragma unroll
    for (int e = 0; e < 8; e++) q[e] = f2bf(ld[ku * 8 + e][j]);
    *(uint4*)(dst + ((long)(jti * kctot + kc) * 64 + kg * 16 + cl) * 8) = *(uint4*)q;
}

// pack x f32 [N][T][D] -> xP tiles over m=n*T+t: tile = t*8 + (n>>4), rows = n&15.
__global__ void k_pack_x2(const float* __restrict__ x, unsigned short* __restrict__ xP) {
    long gid = (long)blockIdx.x * 256 + threadIdx.x;   // 8192*128
    int m = (int)(gid >> 7), u = (int)(gid & 127);
    const float* src = x + (long)m * 1024 + u * 8;
    int n = m >> 6, t = m & 63;
    int tile = t * 8 + (n >> 4);
    int kc = u >> 2, kg = u & 3, cl = n & 15;
    float4 a = *(const float4*)src, b = *(const float4*)(src + 4);
    unsigned short q[8] = {f2bf(a.x), f2bf(a.y), f2bf(a.z), f2bf(a.w),
                           f2bf(b.x), f2bf(b.y), f2bf(b.z), f2bf(b.w)};
    *(uint4*)(xP + ((long)(tile * 32 + kc) * 64 + kg * 16 + cl) * 8) = *(uint4*)q;
}

// A f32 [N][H][16] -> AfP (A-operand tiles: tile=n, row=p, k=h) + Af2 bf16 copy.
__global__ void k_pack_af(const float* __restrict__ A, unsigned short* __restrict__ AfP,
                          unsigned short* __restrict__ Af2) {
    __shared__ float ld[64][17];
    int n = blockIdx.x, h0 = blockIdx.y * 64;
    int tid = threadIdx.x;
    int hh = tid >> 2, pq = tid & 3;
    float4 v = *(const float4*)(A + ((long)n * H_ + h0 + hh) * 16 + pq * 4);
    unsigned short o[4] = {f2bf(v.x), f2bf(v.y), f2bf(v.z), f2bf(v.w)};
    *(uint2*)(Af2 + ((long)n * H_ + h0 + hh) * 16 + pq * 4) = *(uint2*)o;
    ld[hh][pq * 4 + 0] = v.x; ld[hh][pq * 4 + 1] = v.y;
    ld[hh][pq * 4 + 2] = v.z; ld[hh][pq * 4 + 3] = v.w;
    __syncthreads();
    if (tid < 128) {
        int p = tid >> 3, ku = tid & 7;
        int kc = (h0 >> 5) + (ku >> 2), kg = ku & 3;
        unsigned short q[8];
        #pragma unroll
        for (int e = 0; e < 8; e++) q[e] = f2bf(ld[ku * 8 + e][p]);
        *(uint4*)(AfP + ((long)(n * 32 + kc) * 64 + kg * 16 + p) * 8) = *(uint4*)q;
    }
}

// h0 = mean_p A; c0 = h0; packed h0.
__global__ void k_h0(const float* __restrict__ A, float* __restrict__ h,
                     float* __restrict__ c, unsigned short* __restrict__ hP0) {
    long id = (long)blockIdx.x * 256 + threadIdx.x;
    const float4* ap = (const float4*)(A + id * 16);
    float s = 0.f;
    #pragma unroll
    for (int q = 0; q < 4; q++) { float4 v = ap[q]; s += v.x + v.y + v.z + v.w; }
    float m = s * (1.0f / 16.0f);
    h[id] = m; c[id] = m;
    int n = (int)(id >> 10), j = (int)(id & 1023);
    hP0[((long)((n >> 4) * 32 + (j >> 5)) * 64 + ((j >> 3) & 3) * 16 + (n & 15)) * 8 + (j & 7)] = f2bf(m);
}

// t=0 score partials (R8-proven)
__global__ __launch_bounds__(512)
void k_part0(const float* __restrict__ hbuf, const unsigned short* __restrict__ Af2,
             float* __restrict__ partial0) {
    int n = blockIdx.x;
    int tid = threadIdx.x;
    int jh = tid * 2;
    float sp[16];
    #pragma unroll
    for (int p = 0; p < 16; p++) sp[p] = 0.f;
    #pragma unroll
    for (int u = 0; u < 2; u++) {
        float hv = hbuf[(long)n * H_ + jh + u];
        const unsigned short* afp = Af2 + ((long)n * H_ + jh + u) * 16;
        bf16x8 a0 = *(const bf16x8*)(afp);
        bf16x8 a1 = *(const bf16x8*)(afp + 8);
        #pragma unroll
        for (int p = 0; p < 8; p++) { sp[p] += hv * bf2f((unsigned short)a0[p]);
                                      sp[8+p] += hv * bf2f((unsigned short)a1[p]); }
    }
    #pragma unroll
    for (int off = 1; off < 8; off <<= 1) {
        #pragma unroll
        for (int p = 0; p < 16; p++) sp[p] += __shfl_xor(sp[p], off);
    }
    int jt = tid >> 3;
    if ((tid & 7) == 0) {
        #pragma unroll
        for (int p = 0; p < 16; p++)
            partial0[((long)n * 16 + p) * 64 + jt] = sp[p];
    }
}

// AW = AfP @ WattnP^T, fully packed loads. 128x128 block tile, 4 waves (2x2),
// wave 64x64 (4mi x 4ni), K=1024: 32 chunks x (4A + 4B contiguous 1KB -> 16 MFMA).
__global__ __launch_bounds__(256, 2)
void k_aw(const unsigned short* __restrict__ AfP, const unsigned short* __restrict__ WattnP,
          unsigned short* __restrict__ AW) {
    int tid = threadIdx.x;
    int wv = tid >> 6, lane = tid & 63;
    int wr = wv >> 1, wc = wv & 1;
    int cl = lane & 15, kg = lane >> 4;
    int at0 = blockIdx.x * 8 + wr * 4;    // A tiles (= image n)
    int jt0 = blockIdx.y * 8 + wc * 4;    // B tiles

    f32x4 acc[4][4];
    #pragma unroll
    for (int i = 0; i < 4; i++)
        #pragma unroll
        for (int j = 0; j < 4; j++) acc[i][j] = (f32x4){0.f, 0.f, 0.f, 0.f};

    const unsigned short* apx[4];
    const unsigned short* bpx[4];
    #pragma unroll
    for (int i = 0; i < 4; i++) {
        apx[i] = AfP    + (long)(at0 + i) * (32 * 512) + lane * 8;
        bpx[i] = WattnP + (long)(jt0 + i) * (32 * 512) + lane * 8;
    }
    #pragma unroll 2
    for (int kc = 0; kc < 32; kc++) {
        bf16x8 a[4], b[4];
        #pragma unroll
        for (int i = 0; i < 4; i++) a[i] = *(const bf16x8*)(apx[i] + kc * 512);
        #pragma unroll
        for (int i = 0; i < 4; i++) b[i] = *(const bf16x8*)(bpx[i] + kc * 512);
        #pragma unroll
        for (int i = 0; i < 4; i++)
            #pragma unroll
            for (int j = 0; j < 4; j++)
                acc[i][j] = __builtin_amdgcn_mfma_f32_16x16x32_bf16(a[i], b[j], acc[i][j], 0, 0, 0);
    }
    // C write: AW[(n*4096 + j)*16 + p], n = A-tile, p = 4*kg + v, j = jtile*16 + cl
    #pragma unroll
    for (int i = 0; i < 4; i++) {
        int n = at0 + i;
        #pragma unroll
        for (int j = 0; j < 4; j++) {
            int jj = (jt0 + j) * 16 + cl;
            #pragma unroll
            for (int v = 0; v < 4; v++) {
                int p = kg * 4 + v;
                AW[((long)n * G4_ + jj) * 16 + p] = f2bf(acc[i][j][v]);
            }
        }
    }
}

// ------------------------------------------------------------- per step ----

// tiny score: reduce partial[n][p][64] -> softmax -> w[n][16]. (R8-proven)
__global__ __launch_bounds__(64)
void k_score_tiny(const float* __restrict__ partial, float* __restrict__ wbuf) {
    int n = blockIdx.x;
    int lane = threadIdx.x;
    int p = lane & 15, c4 = lane >> 4;
    const float* src = partial + ((long)n * 16 + p) * 64 + c4 * 16;
    float s = 0.f;
    #pragma unroll
    for (int q = 0; q < 16; q++) s += src[q];
    s += __shfl_xor(s, 16);
    s += __shfl_xor(s, 32);
    s *= (1.0f / 32.0f);
    float m = s;
    #pragma unroll
    for (int off = 1; off < 16; off <<= 1) m = fmaxf(m, __shfl_xor(m, off));
    float e = expf(s - m);
    float sum = e;
    #pragma unroll
    for (int off = 1; off < 16; off <<= 1) sum += __shfl_xor(sum, off);
    if (c4 == 0) wbuf[n * 16 + p] = e / sum;
}

// Fused step (R8 structure, fully packed loads): act = [xt|h] @ Wxh^T (+ w.AW + b).
// grid (64 jt, 8 nt), 256 thr = 4 waves = K-quarters (512 each = 16 kc-chunks).
// Per chunk: 1 A-load + 4 B-loads (1KB contiguous each) -> 4 MFMA.
__global__ __launch_bounds__(256, 2)
void k_step(const unsigned short* __restrict__ xP,      // packed x
            const unsigned short* __restrict__ hPin,    // packed h
            unsigned short* __restrict__ hPout,
            const unsigned short* __restrict__ WxhP,    // [256 jti][64 kc][512]
            const unsigned short* __restrict__ AW,      // [N][4096][16]
            const unsigned short* __restrict__ Af2,     // [N][H][16]
            const float* __restrict__ wbuf,             // [N][16]
            const float* __restrict__ bvec,             // [4096]
            float* __restrict__ c,
            float* __restrict__ partOUT,                // [N][16][64]
            float* __restrict__ out, int t) {
    int tid = threadIdx.x;
    int ks = tid >> 6, lane = tid & 63;
    int cl = lane & 15, kg = lane >> 4;
    int jt = blockIdx.x;
    int nt = blockIdx.y;
    int colbase = jt * 16, rowbase = nt * 16;

    // ---- GEMM ----
    f32x4 acc[4];
    #pragma unroll
    for (int g = 0; g < 4; g++) acc[g] = (f32x4){0.f, 0.f, 0.f, 0.f};

    const unsigned short* abase = (ks < 2)
        ? xP  + ((long)(t * 8 + nt) * 32 + ks * 16) * 512 + lane * 8
        : hPin + ((long)nt * 32 + (ks - 2) * 16) * 512 + lane * 8;
    const unsigned short* bb[4];
    #pragma unroll
    for (int g = 0; g < 4; g++)
        bb[g] = WxhP + ((long)(g * 64 + jt) * 64 + ks * 16) * 512 + lane * 8;

    #pragma unroll
    for (int i = 0; i < 16; i++) {
        bf16x8 a = *(const bf16x8*)(abase + i * 512);
        #pragma unroll
        for (int g = 0; g < 4; g++) {
            bf16x8 b = *(const bf16x8*)(bb[g] + i * 512);
            acc[g] = __builtin_amdgcn_mfma_f32_16x16x32_bf16(a, b, acc[g], 0, 0, 0);
        }
    }

    // ---- 4-way K reduce (R8) ----
    __shared__ float red[3][64][17];
    __shared__ float act[4][16][17];
    if (ks != 0) {
        #pragma unroll
        for (int g = 0; g < 4; g++)
            #pragma unroll
            for (int v = 0; v < 4; v++) red[ks - 1][lane][g * 4 + v] = acc[g][v];
    }
    __syncthreads();
    if (ks == 0) {
        #pragma unroll
        for (int g = 0; g < 4; g++)
            #pragma unroll
            for (int v = 0; v < 4; v++) {
                float s = acc[g][v] + red[0][lane][g*4+v] + red[1][lane][g*4+v] + red[2][lane][g*4+v];
                act[g][kg * 4 + v][cl] = s;   // C/D row = 4*kg + v
            }
    }
    __syncthreads();

    // ---- epilogue: 256 thr x 1 (n, jh) cell (R8) ----
    int nloc = tid >> 4, jl = tid & 15;
    int n = rowbase + nloc, jh = colbase + jl;
    float wv16[16];
    #pragma unroll
    for (int p = 0; p < 16; p++) wv16[p] = wbuf[n * 16 + p];

    float s4[4];
    #pragma unroll
    for (int g = 0; g < 4; g++) {
        int j = g * 1024 + jh;
        const unsigned short* awp = AW + ((long)n * G4_ + j) * 16;
        bf16x8 aw0 = *(const bf16x8*)(awp);
        bf16x8 aw1 = *(const bf16x8*)(awp + 8);
        float at = 0.f;
        #pragma unroll
        for (int p = 0; p < 8; p++) at += wv16[p]     * bf2f((unsigned short)aw0[p]);
        #pragma unroll
        for (int p = 0; p < 8; p++) at += wv16[8 + p] * bf2f((unsigned short)aw1[p]);
        s4[g] = act[g][nloc][jl] + at + bvec[j];
    }
    float ig = 1.f / (1.f + expf(-s4[0]));
    float fg = 1.f / (1.f + expf(-s4[1]));
    float og = 1.f / (1.f + expf(-s4[2]));
    float gg = tanhf(s4[3]);
    long idx = (long)n * H_ + jh;
    float cn = fg * c[idx] + ig * gg;
    float hn = og * tanhf(cn);
    c[idx] = cn;
    out[((long)n * T_ + t) * H_ + jh] = hn;
    // packed h write
    hPout[((long)((n >> 4) * 32 + (jh >> 5)) * 64 + ((jh >> 3) & 3) * 16 + (n & 15)) * 8 + (jh & 7)] = f2bf(hn);

    // score partials for t+1 (R8)
    const unsigned short* afp = Af2 + ((long)n * H_ + jh) * 16;
    bf16x8 af0 = *(const bf16x8*)(afp);
    bf16x8 af1 = *(const bf16x8*)(afp + 8);
    float sp[16];
    #pragma unroll
    for (int p = 0; p < 8; p++) { sp[p]     = hn * bf2f((unsigned short)af0[p]);
                                  sp[8 + p] = hn * bf2f((unsigned short)af1[p]); }
    #pragma unroll
    for (int off = 1; off < 16; off <<= 1) {
        #pragma unroll
        for (int p = 0; p < 16; p++) sp[p] += __shfl_xor(sp[p], off);
    }
    float outv = 0.f;
    #pragma unroll
    for (int p = 0; p < 16; p++) if (jl == p) outv = sp[p];
    partOUT[((long)n * 16 + jl) * 64 + jt] = outv;
}

// ---------------------------------------------------------------- launch ----

extern "C" void kernel_launch(void* const* d_in, const int* in_sizes, int n_in,
                              void* d_out, int out_size, void* d_ws, size_t ws_size,
                              hipStream_t stream) {
    const float* x     = (const float*)d_in[0];
    const float* A     = (const float*)d_in[1];
    const float* Wx    = (const float*)d_in[2];
    const float* Wh    = (const float*)d_in[3];
    const float* Wattn = (const float*)d_in[4];
    const float* b     = (const float*)d_in[5];
    float* out = (float*)d_out;

    char* ws = (char*)d_ws;
    size_t off = 0;
    auto alloc = [&](size_t bytes) -> void* {
        void* p = ws + off;
        off += (bytes + 255) & ~(size_t)255;
        return p;
    };
    unsigned short* xP     = (unsigned short*)alloc((size_t)512 * 32 * 512 * 2);   // 16.8MB
    unsigned short* WxhP   = (unsigned short*)alloc((size_t)256 * 64 * 512 * 2);   // 16.8MB
    unsigned short* WattnP = (unsigned short*)alloc((size_t)256 * 32 * 512 * 2);   // 8.4MB
    unsigned short* AfP    = (unsigned short*)alloc((size_t)128 * 32 * 512 * 2);   // 4.2MB
    unsigned short* Af2    = (unsigned short*)alloc((size_t)N_ * H_ * 16 * 2);     // 4.2MB
    unsigned short* AW     = (unsigned short*)alloc((size_t)N_ * G4_ * 16 * 2);    // 16.8MB
    float*          hbuf   = (float*)alloc((size_t)N_ * H_ * 4);
    float*          cbuf   = (float*)alloc((size_t)N_ * H_ * 4);
    unsigned short* hP0    = (unsigned short*)alloc((size_t)8 * 32 * 512 * 2);
    unsigned short* hP1    = (unsigned short*)alloc((size_t)8 * 32 * 512 * 2);
    float*          part0  = (float*)alloc((size_t)N_ * 16 * 64 * 4);
    float*          part1  = (float*)alloc((size_t)N_ * 16 * 64 * 4);
    float*          wbuf   = (float*)alloc((size_t)N_ * 16 * 4);

    // prep
    k_pack_w<<<dim3(128, 16), dim3(256), 0, stream>>>(Wx,    WxhP,   0,  64);
    k_pack_w<<<dim3(128, 16), dim3(256), 0, stream>>>(Wh,    WxhP,   32, 64);
    k_pack_w<<<dim3(128, 16), dim3(256), 0, stream>>>(Wattn, WattnP, 0,  32);
    k_pack_x2<<<dim3(4096), dim3(256), 0, stream>>>(x, xP);
    k_pack_af<<<dim3(128, 16), dim3(256), 0, stream>>>(A, AfP, Af2);
    k_h0<<<dim3(512), dim3(256), 0, stream>>>(A, hbuf, cbuf, hP0);
    k_part0<<<dim3(N_), dim3(512), 0, stream>>>(hbuf, Af2, part0);
    k_aw<<<dim3(16, 32), dim3(256), 0, stream>>>(AfP, WattnP, AW);

    // recurrence
    for (int t = 0; t < T_; t++) {
        unsigned short* hin  = (t & 1) ? hP1 : hP0;
        unsigned short* hout = (t & 1) ? hP0 : hP1;
        float* pIN  = (t & 1) ? part1 : part0;
        float* pOUT = (t & 1) ? part0 : part1;
        k_score_tiny<<<dim3(N_), dim3(64), 0, stream>>>(pIN, wbuf);
        k_step<<<dim3(64, 8), dim3(256), 0, stream>>>(xP, hin, hout, WxhP, AW, Af2,
                                                      wbuf, b, cbuf, pOUT, out, t);
    }
}